// Round 17
// baseline (132.649 us; speedup 1.0000x reference)
//
#include <hip/hip_runtime.h>
#include <hip/hip_bf16.h>

typedef __attribute__((ext_vector_type(8))) short short8;
typedef __attribute__((ext_vector_type(4))) float f32x4;

#define SC_L2E 0.4561727848849353f          // (1/sqrt(10)) * log2(e)

#if __has_builtin(__builtin_amdgcn_exp2f)
#define EXP2F __builtin_amdgcn_exp2f
#else
#define EXP2F exp2f
#endif

static __device__ __forceinline__ void gload16(const void* g, void* l) {
  __builtin_amdgcn_global_load_lds((const __attribute__((address_space(1))) void*)g,
                                   (__attribute__((address_space(3))) void*)l, 16, 0, 0);
}

// ---------------- kernel 1: fused converts (r9-verified) ----------------
__global__ void k_cvt(const float* __restrict__ q, const float* __restrict__ kk,
                      const float* __restrict__ v, __hip_bfloat16* __restrict__ xb,
                      const float* __restrict__ Wq, const float* __restrict__ Wk,
                      const float* __restrict__ Wv, __hip_bfloat16* __restrict__ wt,
                      const int* __restrict__ mask, float* __restrict__ bias2) {
  __shared__ float T[64][65];
  if (blockIdx.x < 6144) {
    const size_t i = ((size_t)blockIdx.x * 256 + threadIdx.x) * 8;
    const int t = (int)(i >> 22);               // 4194304 elements per tensor
    const float* src = (t == 0) ? q : (t == 1) ? kk : v;
    const size_t off = i & 4194303u;
    float4 f0 = *(const float4*)(src + off);
    float4 f1 = *(const float4*)(src + off + 4);
    union { short8 s; __hip_bfloat16 h[8]; } u;
    u.h[0] = __float2bfloat16(f0.x); u.h[1] = __float2bfloat16(f0.y);
    u.h[2] = __float2bfloat16(f0.z); u.h[3] = __float2bfloat16(f0.w);
    u.h[4] = __float2bfloat16(f1.x); u.h[5] = __float2bfloat16(f1.y);
    u.h[6] = __float2bfloat16(f1.z); u.h[7] = __float2bfloat16(f1.w);
    *(short8*)((char*)xb + i * 2) = u.s;
    return;
  }
  const int idx2 = blockIdx.x - 6144;           // 0..767
  const int z = idx2 >> 8;                      // 0..2
  const int r2 = idx2 & 255;
  const int bxi = r2 & 15, byi = r2 >> 4;
  if (z == 0 && byi == 0) {
    const int idx = bxi * 256 + threadIdx.x;
    bias2[idx] = mask[idx] ? -12.0f : -1e30f;   // static shift M=12 folded in
  }
  const float* W = (z == 0) ? Wq : (z == 1) ? Wk : Wv;
  __hip_bfloat16* Wd = wt + (size_t)z * 1048576;
  const int n0 = bxi * 64, k0 = byi * 64;
  const int tx = threadIdx.x & 63, ty = threadIdx.x >> 6;
#pragma unroll
  for (int r = 0; r < 16; ++r)
    T[ty + r * 4][tx] = W[(size_t)(k0 + ty + r * 4) * 1024 + n0 + tx];
  __syncthreads();
#pragma unroll
  for (int r = 0; r < 16; ++r)
    Wd[(size_t)(n0 + ty + r * 4) * 1024 + k0 + tx] = __float2bfloat16(T[tx][ty + r * 4]);
}

// ---------------- kernel 2: projection GEMM (r12-verified) ----------------
__global__ __launch_bounds__(256) void k_proj(
    const __hip_bfloat16* __restrict__ xb, const __hip_bfloat16* __restrict__ wt,
    const float* __restrict__ bq, const float* __restrict__ bk, const float* __restrict__ bv,
    __hip_bfloat16* __restrict__ Qb, __hip_bfloat16* __restrict__ Kb,
    __hip_bfloat16* __restrict__ Vt) {
  __shared__ char smem[32768];
  char* As = smem;            // [128 rows][64 bf16] = 128 B rows, 16 KB
  char* Bs = smem + 16384;
  const int orig = blockIdx.x;
  const int xcd = orig & 7, idx = orig >> 3;    // idx 0..95
  const int by = xcd * 4 + (idx & 3);           // 0..31
  const int bx = (idx >> 2) & 7;                // 0..7
  const int t = idx >> 5;                       // 0..2
  const char* X = (const char*)(xb + (size_t)t * 4194304);
  const char* W = (const char*)(wt + (size_t)t * 1048576);
  const float* bias = (t == 0) ? bq : (t == 1) ? bk : bv;
  const int m0 = by * 128, n0 = bx * 128;
  const int tid = threadIdx.x, w = tid >> 6, lane = tid & 63;
  const int l15 = lane & 15, g = lane >> 4;
  const int l8 = lane >> 3, l7 = lane & 7;
  const int vswz = ((l7 ^ l8) << 4);            // pre-swizzled 16B slot in 128B row
  const int wm = (w >> 1) * 64, wn = (w & 1) * 64;
  f32x4 acc[4][4];
#pragma unroll
  for (int i = 0; i < 4; ++i)
#pragma unroll
    for (int j = 0; j < 4; ++j) acc[i][j] = (f32x4){0.f, 0.f, 0.f, 0.f};

  for (int k0 = 0; k0 < 2048; k0 += 128) {      // 16 K-steps of 64 elems
    __syncthreads();
#pragma unroll
    for (int j = 0; j < 4; ++j) {
      const int ch = w * 4 + j;                 // 16 chunks of 8 rows
      gload16(X + (size_t)(m0 + ch * 8 + l8) * 2048 + k0 + vswz, As + ch * 1024);
      gload16(W + (size_t)(n0 + ch * 8 + l8) * 2048 + k0 + vswz, Bs + ch * 1024);
    }
    __syncthreads();
#pragma unroll
    for (int kk = 0; kk < 2; ++kk) {
      short8 af[4], bf_[4];
#pragma unroll
      for (int mt = 0; mt < 4; ++mt) {
        const int row = wm + mt * 16 + l15;
        af[mt] = *(const short8*)(As + row * 128 + ((kk * 64 + g * 16) ^ ((row & 7) << 4)));
      }
#pragma unroll
      for (int nt = 0; nt < 4; ++nt) {
        const int row = wn + nt * 16 + l15;
        bf_[nt] = *(const short8*)(Bs + row * 128 + ((kk * 64 + g * 16) ^ ((row & 7) << 4)));
      }
#pragma unroll
      for (int mt = 0; mt < 4; ++mt)
#pragma unroll
        for (int nt = 0; nt < 4; ++nt)
          acc[mt][nt] = __builtin_amdgcn_mfma_f32_16x16x32_bf16(af[mt], bf_[nt], acc[mt][nt], 0, 0, 0);
    }
  }

  float bv4[4];
#pragma unroll
  for (int nt = 0; nt < 4; ++nt) bv4[nt] = bias[n0 + wn + nt * 16 + l15];

  if (t < 2) {
    // Q/K epilogue: direct scatter (verified path)
#pragma unroll
    for (int mt = 0; mt < 4; ++mt) {
#pragma unroll
      for (int nt = 0; nt < 4; ++nt) {
        const int feat = n0 + wn + nt * 16 + l15;
        const int h = feat >> 6, d = feat & 63;
#pragma unroll
        for (int r = 0; r < 4; ++r) {
          const int token = m0 + wm + mt * 16 + g * 4 + r;
          const int b = token >> 11, s = token & 2047;
          const float val = acc[mt][nt][r] + bv4[nt];
          const __hip_bfloat16 hb = __float2bfloat16(val);
          if (t == 0) Qb[((size_t)(b * 16 + h) * 2048 + s) * 64 + d] = hb;
          else        Kb[((size_t)(b * 16 + h) * 2048 + s) * 64 + d] = hb;
        }
      }
    }
  } else {
    // V epilogue: LDS transpose -> coalesced stores, NATURAL key order (r7-verified)
    __hip_bfloat16* T2 = (__hip_bfloat16*)smem;
    const int bb = m0 >> 11;
    const int s0 = m0 & 2047;
#pragma unroll
    for (int p = 0; p < 2; ++p) {
      __syncthreads();
      if ((w >> 1) == p) {
#pragma unroll
        for (int mt = 0; mt < 4; ++mt)
#pragma unroll
          for (int nt = 0; nt < 4; ++nt) {
            const int feat = wn + nt * 16 + l15;
#pragma unroll
            for (int r = 0; r < 4; ++r) {
              const int tok = mt * 16 + g * 4 + r;
              T2[feat * 64 + (tok ^ ((feat & 7) << 3))] =
                  __float2bfloat16(acc[mt][nt][r] + bv4[nt]);
            }
          }
      }
      __syncthreads();
#pragma unroll
      for (int sw = 0; sw < 4; ++sw) {
        const int row = sw * 32 + (tid >> 3);
        const int c = tid & 7;
        const short8 vchunk = *(const short8*)(smem + row * 128 + 16 * (c ^ (row & 7)));
        const int gfeat = n0 + row;
        const int hh = gfeat >> 6, dd = gfeat & 63;
        *(short8*)(Vt + ((size_t)((bb * 16 + hh) * 64 + dd)) * 2048 + s0 + p * 64 + c * 8) = vchunk;
      }
    }
  }
}

// ---------------- kernel 3: flash attention (K in LDS, V in registers) ---------
// 512 blocks (XCD-swizzled) x 256 threads (4 waves x 32 q). K triple-buffered in
// LDS (permuted staging, all-K=32 MFMA); V loaded PRIVATELY to 32 VGPRs per wave
// (natural V^T layout, same bytes as old LDS path), issued after PV(t) for t+1
// -> one-body latency cover, no LDS/barrier involvement for V. Counted vmcnt(10)
// leaves K(t+2)x2 + V(t+1)x8 in flight across the barrier.
#define ATTN_BODY(CUR, PRF, DOK, DOV, VM)                                      \
  {                                                                            \
    float4 mb[4];                                                              \
    _Pragma("unroll") for (int nt = 0; nt < 4; ++nt)                           \
        mb[nt] = *(const float4*)(mbp + (nt >> 1) * 32 + ((nt & 1) << 2) + g * 8); \
    mbp += 64;                                                                 \
    __builtin_amdgcn_sched_barrier(0);  /* mb loads issue before gloads */     \
    if (DOK) {                                                                 \
      _Pragma("unroll") for (int j = 0; j < 2; ++j)                            \
        gload16(kst[j], Ks[PRF] + (w * 2 + j) * 1024);                         \
    }                                                                          \
    kst[0] += 8192; kst[1] += 8192;                                            \
    f32x4 sA[4], sB[4];                                                        \
    __builtin_amdgcn_s_setprio(1);                                             \
    _Pragma("unroll") for (int nt = 0; nt < 4; ++nt) {                         \
      const int key = nt * 16 + l15;                                           \
      const int ksw = (key & 7) << 4;                                          \
      const short8 kf0 = *(const short8*)(Ks[CUR] + key * 128 + ((g * 16) ^ ksw)); \
      const short8 kf1 = *(const short8*)(Ks[CUR] + key * 128 + ((64 + g * 16) ^ ksw)); \
      f32x4 z = (f32x4){0.f, 0.f, 0.f, 0.f};                                   \
      sA[nt] = __builtin_amdgcn_mfma_f32_16x16x32_bf16(kf0, aq[0][0], z, 0, 0, 0); \
      sA[nt] = __builtin_amdgcn_mfma_f32_16x16x32_bf16(kf1, aq[0][1], sA[nt], 0, 0, 0); \
      sB[nt] = __builtin_amdgcn_mfma_f32_16x16x32_bf16(kf0, aq[1][0], z, 0, 0, 0); \
      sB[nt] = __builtin_amdgcn_mfma_f32_16x16x32_bf16(kf1, aq[1][1], sB[nt], 0, 0, 0); \
    }                                                                          \
    __builtin_amdgcn_s_setprio(0);                                             \
    short8 pbA[2], pbB[2];                                                     \
    _Pragma("unroll") for (int c = 0; c < 2; ++c) {                            \
      union { short8 s8; __hip_bfloat16 hh[8]; } pa, pb;                       \
      _Pragma("unroll") for (int e = 0; e < 8; ++e) {                          \
        const int nt = 2 * c + (e >> 2);                                       \
        const float mbe = (e & 3) == 0 ? mb[nt].x : (e & 3) == 1 ? mb[nt].y :  \
                          (e & 3) == 2 ? mb[nt].z : mb[nt].w;                  \
        pa.hh[e] = __float2bfloat16(EXP2F(fmaf(sA[nt][e & 3], SC_L2E, mbe)));  \
        pb.hh[e] = __float2bfloat16(EXP2F(fmaf(sB[nt][e & 3], SC_L2E, mbe)));  \
      }                                                                        \
      pbA[c] = pa.s8; pbB[c] = pb.s8;                                          \
    }                                                                          \
    __builtin_amdgcn_s_setprio(1);                                             \
    laccA = __builtin_amdgcn_mfma_f32_16x16x32_bf16(ones8, pbA[0], laccA, 0, 0, 0); \
    laccA = __builtin_amdgcn_mfma_f32_16x16x32_bf16(ones8, pbA[1], laccA, 0, 0, 0); \
    laccB = __builtin_amdgcn_mfma_f32_16x16x32_bf16(ones8, pbB[0], laccB, 0, 0, 0); \
    laccB = __builtin_amdgcn_mfma_f32_16x16x32_bf16(ones8, pbB[1], laccB, 0, 0, 0); \
    _Pragma("unroll") for (int dt = 0; dt < 4; ++dt) {                         \
      f32x4 oa = oaccA[dt], ob = oaccB[dt];                                    \
      oa = __builtin_amdgcn_mfma_f32_16x16x32_bf16(vr0[dt], pbA[0], oa, 0, 0, 0); \
      oa = __builtin_amdgcn_mfma_f32_16x16x32_bf16(vr1[dt], pbA[1], oa, 0, 0, 0); \
      ob = __builtin_amdgcn_mfma_f32_16x16x32_bf16(vr0[dt], pbB[0], ob, 0, 0, 0); \
      ob = __builtin_amdgcn_mfma_f32_16x16x32_bf16(vr1[dt], pbB[1], ob, 0, 0, 0); \
      oaccA[dt] = oa; oaccB[dt] = ob;                                          \
    }                                                                          \
    __builtin_amdgcn_s_setprio(0);                                             \
    if (DOV) {                                                                 \
      _Pragma("unroll") for (int dt = 0; dt < 4; ++dt) {                       \
        vr0[dt] = *(const short8*)(vp[dt]);                                    \
        vr1[dt] = *(const short8*)(vp[dt] + 64);                               \
        vp[dt] += 128;                                                         \
      }                                                                        \
    }                                                                          \
    if (VM == 10) { asm volatile("s_waitcnt vmcnt(10)" ::: "memory"); }        \
    else if (VM == 8) { asm volatile("s_waitcnt vmcnt(8)" ::: "memory"); }     \
    if (VM >= 0) {                                                             \
      __builtin_amdgcn_s_barrier();                                            \
      __builtin_amdgcn_sched_barrier(0);                                       \
    }                                                                          \
  }

__global__ __launch_bounds__(256, 2) void k_attn(
    const __hip_bfloat16* __restrict__ Qb, const __hip_bfloat16* __restrict__ Kb,
    const __hip_bfloat16* __restrict__ Vt, const float* __restrict__ bias2,
    float* __restrict__ out) {
  __shared__ char Ks[3][8192];              // [64 key-slots][64 d] bf16, permuted keys
  const int orig = blockIdx.x;
  const int swz = (orig & 7) * 64 + (orig >> 3);   // bijective; 4 heads per XCD
  const int bh = swz >> 4, qb = swz & 15;
  const int b = bh >> 4, h = bh & 15;
  const int tid = threadIdx.x, w = tid >> 6, lane = tid & 63;
  const int g = lane >> 4, l15 = lane & 15;
  const char* Qc = (const char*)(Qb + (size_t)bh * 131072);
  const char* Kc = (const char*)(Kb + (size_t)bh * 131072);
  const char* Vc = (const char*)(Vt + (size_t)bh * 131072);

  const int l8 = lane >> 3, l7 = lane & 7;
  const int vswz = ((l7 ^ l8) << 4);        // pre-swizzled global 16B slot in 128B row

  // Q B-fragments for the wave's TWO q-tiles
  short8 aq[2][2];
  const int arow0 = qb * 128 + w * 32 + l15;
#pragma unroll
  for (int qt = 0; qt < 2; ++qt)
#pragma unroll
    for (int kc = 0; kc < 2; ++kc)
      aq[qt][kc] = *(const short8*)(Qc + (size_t)(arow0 + qt * 16) * 128 + kc * 64 + g * 16);

  f32x4 oaccA[4], oaccB[4];
#pragma unroll
  for (int i = 0; i < 4; ++i) {
    oaccA[i] = (f32x4){0.f, 0.f, 0.f, 0.f};
    oaccB[i] = (f32x4){0.f, 0.f, 0.f, 0.f};
  }
  f32x4 laccA = (f32x4){0.f, 0.f, 0.f, 0.f};
  f32x4 laccB = (f32x4){0.f, 0.f, 0.f, 0.f};
  const short8 ones8 = {(short)0x3F80, (short)0x3F80, (short)0x3F80, (short)0x3F80,
                        (short)0x3F80, (short)0x3F80, (short)0x3F80, (short)0x3F80};

  // K staging pointers (permuted key map, r12-verified)
  const char* kst[2];
#pragma unroll
  for (int j = 0; j < 2; ++j) {
    const int ch = w * 2 + j;
    const int s = ch * 8 + l8;
    const int nt0 = s >> 4, gg = (s >> 2) & 3, rr = s & 3;
    const int kap = (nt0 >> 1) * 32 + gg * 8 + ((nt0 & 1) << 2) + rr;
    kst[j] = Kc + (size_t)kap * 128 + vswz;
  }
  // V private pointers + register tile (natural V^T layout)
  const char* vp[4];
#pragma unroll
  for (int dt = 0; dt < 4; ++dt)
    vp[dt] = Vc + (size_t)(dt * 16 + l15) * 4096 + g * 16;
  short8 vr0[4], vr1[4];

  // prologue: issue K(0), K(1) to LDS, then V(0) to regs
#pragma unroll
  for (int tpre = 0; tpre < 2; ++tpre) {
#pragma unroll
    for (int j = 0; j < 2; ++j)
      gload16(kst[j], Ks[tpre] + (w * 2 + j) * 1024);
    kst[0] += 8192; kst[1] += 8192;
  }
#pragma unroll
  for (int dt = 0; dt < 4; ++dt) {
    vr0[dt] = *(const short8*)(vp[dt]);
    vr1[dt] = *(const short8*)(vp[dt] + 64);
    vp[dt] += 128;
  }
  asm volatile("s_waitcnt vmcnt(10)" ::: "memory");  // K(0) landed; K(1)+V(0) in flight
  __builtin_amdgcn_s_barrier();
  __builtin_amdgcn_sched_barrier(0);

  const float* mbp = bias2 + b * 2048;
  for (int k = 0; k < 10; ++k) {            // bodies 0..29 (K prefetch t+2 <= 31)
    ATTN_BODY(0, 2, 1, 1, 10)
    ATTN_BODY(1, 0, 1, 1, 10)
    ATTN_BODY(2, 1, 1, 1, 10)
  }
  ATTN_BODY(0, 2, 0, 1, 8)                  // t=30: issue V(31); K(31) already landed
  ATTN_BODY(1, 0, 0, 0, -1)                 // t=31: compute only

  // epilogue: per q-tile, lacc rows all equal the full denominator
  const float rlA = 1.0f / laccA[0];
  const float rlB = 1.0f / laccB[0];
  float* orowA = out + ((size_t)(b * 2048 + arow0)) * 1024 + h * 64;
  float* orowB = orowA + 16 * 1024;
#pragma unroll
  for (int dt = 0; dt < 4; ++dt) {
    float4 stA, stB;
    stA.x = oaccA[dt][0] * rlA; stA.y = oaccA[dt][1] * rlA;
    stA.z = oaccA[dt][2] * rlA; stA.w = oaccA[dt][3] * rlA;
    stB.x = oaccB[dt][0] * rlB; stB.y = oaccB[dt][1] * rlB;
    stB.z = oaccB[dt][2] * rlB; stB.w = oaccB[dt][3] * rlB;
    *(float4*)(orowA + dt * 16 + g * 4) = stA;
    *(float4*)(orowB + dt * 16 + g * 4) = stB;
  }
}

// ---------------- launcher ----------------
extern "C" void kernel_launch(void* const* d_in, const int* in_sizes, int n_in,
                              void* d_out, int out_size, void* d_ws, size_t ws_size,
                              hipStream_t stream) {
  const float* q   = (const float*)d_in[0];
  const float* k   = (const float*)d_in[1];
  const float* v   = (const float*)d_in[2];
  const int* mask  = (const int*)d_in[3];
  const float* Wq  = (const float*)d_in[4];
  const float* bq  = (const float*)d_in[5];
  const float* Wk  = (const float*)d_in[6];
  const float* bk  = (const float*)d_in[7];
  const float* Wv  = (const float*)d_in[8];
  const float* bv  = (const float*)d_in[9];
  float* out = (float*)d_out;
  char* ws = (char*)d_ws;
  __hip_bfloat16* Xb = (__hip_bfloat16*)(ws);
  __hip_bfloat16* Wt = (__hip_bfloat16*)(ws + 25165824);
  __hip_bfloat16* Qb = (__hip_bfloat16*)(ws + 31457280);
  __hip_bfloat16* Kb = (__hip_bfloat16*)(ws + 39845888);
  __hip_bfloat16* Vt = (__hip_bfloat16*)(ws + 48234496);
  float* bias2      = (float*)(ws + 56623104);   // 4096 floats

  k_cvt<<<dim3(6912), dim3(256), 0, stream>>>(q, k, v, Xb, Wq, Wk, Wv, Wt, mask, bias2);
  k_proj<<<dim3(768), dim3(256), 0, stream>>>(Xb, Wt, bq, bk, bv, Qb, Kb, Vt);
  k_attn<<<dim3(512), dim3(256), 0, stream>>>(Qb, Kb, Vt, bias2, out);
}

// Round 18
// 100.240 us; speedup vs baseline: 1.3233x; 1.3233x over previous
//
#include <hip/hip_runtime.h>
#include <hip/hip_bf16.h>

typedef __attribute__((ext_vector_type(8))) short short8;
typedef __attribute__((ext_vector_type(4))) float f32x4;

#define SC_L2E 0.4561727848849353f          // (1/sqrt(10)) * log2(e)

#if __has_builtin(__builtin_amdgcn_exp2f)
#define EXP2F __builtin_amdgcn_exp2f
#else
#define EXP2F exp2f
#endif

static __device__ __forceinline__ void gload16(const void* g, void* l) {
  __builtin_amdgcn_global_load_lds((const __attribute__((address_space(1))) void*)g,
                                   (__attribute__((address_space(3))) void*)l, 16, 0, 0);
}

// ---------------- kernel 1: fused converts (r9-verified) ----------------
__global__ void k_cvt(const float* __restrict__ q, const float* __restrict__ kk,
                      const float* __restrict__ v, __hip_bfloat16* __restrict__ xb,
                      const float* __restrict__ Wq, const float* __restrict__ Wk,
                      const float* __restrict__ Wv, __hip_bfloat16* __restrict__ wt,
                      const int* __restrict__ mask, float* __restrict__ bias2) {
  __shared__ float T[64][65];
  if (blockIdx.x < 6144) {
    const size_t i = ((size_t)blockIdx.x * 256 + threadIdx.x) * 8;
    const int t = (int)(i >> 22);               // 4194304 elements per tensor
    const float* src = (t == 0) ? q : (t == 1) ? kk : v;
    const size_t off = i & 4194303u;
    float4 f0 = *(const float4*)(src + off);
    float4 f1 = *(const float4*)(src + off + 4);
    union { short8 s; __hip_bfloat16 h[8]; } u;
    u.h[0] = __float2bfloat16(f0.x); u.h[1] = __float2bfloat16(f0.y);
    u.h[2] = __float2bfloat16(f0.z); u.h[3] = __float2bfloat16(f0.w);
    u.h[4] = __float2bfloat16(f1.x); u.h[5] = __float2bfloat16(f1.y);
    u.h[6] = __float2bfloat16(f1.z); u.h[7] = __float2bfloat16(f1.w);
    *(short8*)((char*)xb + i * 2) = u.s;
    return;
  }
  const int idx2 = blockIdx.x - 6144;           // 0..767
  const int z = idx2 >> 8;                      // 0..2
  const int r2 = idx2 & 255;
  const int bxi = r2 & 15, byi = r2 >> 4;
  if (z == 0 && byi == 0) {
    const int idx = bxi * 256 + threadIdx.x;
    bias2[idx] = mask[idx] ? -12.0f : -1e30f;   // static shift M=12 folded in
  }
  const float* W = (z == 0) ? Wq : (z == 1) ? Wk : Wv;
  __hip_bfloat16* Wd = wt + (size_t)z * 1048576;
  const int n0 = bxi * 64, k0 = byi * 64;
  const int tx = threadIdx.x & 63, ty = threadIdx.x >> 6;
#pragma unroll
  for (int r = 0; r < 16; ++r)
    T[ty + r * 4][tx] = W[(size_t)(k0 + ty + r * 4) * 1024 + n0 + tx];
  __syncthreads();
#pragma unroll
  for (int r = 0; r < 16; ++r)
    Wd[(size_t)(n0 + ty + r * 4) * 1024 + k0 + tx] = __float2bfloat16(T[tx][ty + r * 4]);
}

// ---------------- kernel 2: projection GEMM (r12-verified) ----------------
__global__ __launch_bounds__(256) void k_proj(
    const __hip_bfloat16* __restrict__ xb, const __hip_bfloat16* __restrict__ wt,
    const float* __restrict__ bq, const float* __restrict__ bk, const float* __restrict__ bv,
    __hip_bfloat16* __restrict__ Qb, __hip_bfloat16* __restrict__ Kb,
    __hip_bfloat16* __restrict__ Vt) {
  __shared__ char smem[32768];
  char* As = smem;            // [128 rows][64 bf16] = 128 B rows, 16 KB
  char* Bs = smem + 16384;
  const int orig = blockIdx.x;
  const int xcd = orig & 7, idx = orig >> 3;    // idx 0..95
  const int by = xcd * 4 + (idx & 3);           // 0..31
  const int bx = (idx >> 2) & 7;                // 0..7
  const int t = idx >> 5;                       // 0..2
  const char* X = (const char*)(xb + (size_t)t * 4194304);
  const char* W = (const char*)(wt + (size_t)t * 1048576);
  const float* bias = (t == 0) ? bq : (t == 1) ? bk : bv;
  const int m0 = by * 128, n0 = bx * 128;
  const int tid = threadIdx.x, w = tid >> 6, lane = tid & 63;
  const int l15 = lane & 15, g = lane >> 4;
  const int l8 = lane >> 3, l7 = lane & 7;
  const int vswz = ((l7 ^ l8) << 4);            // pre-swizzled 16B slot in 128B row
  const int wm = (w >> 1) * 64, wn = (w & 1) * 64;
  f32x4 acc[4][4];
#pragma unroll
  for (int i = 0; i < 4; ++i)
#pragma unroll
    for (int j = 0; j < 4; ++j) acc[i][j] = (f32x4){0.f, 0.f, 0.f, 0.f};

  for (int k0 = 0; k0 < 2048; k0 += 128) {      // 16 K-steps of 64 elems
    __syncthreads();
#pragma unroll
    for (int j = 0; j < 4; ++j) {
      const int ch = w * 4 + j;                 // 16 chunks of 8 rows
      gload16(X + (size_t)(m0 + ch * 8 + l8) * 2048 + k0 + vswz, As + ch * 1024);
      gload16(W + (size_t)(n0 + ch * 8 + l8) * 2048 + k0 + vswz, Bs + ch * 1024);
    }
    __syncthreads();
#pragma unroll
    for (int kk = 0; kk < 2; ++kk) {
      short8 af[4], bf_[4];
#pragma unroll
      for (int mt = 0; mt < 4; ++mt) {
        const int row = wm + mt * 16 + l15;
        af[mt] = *(const short8*)(As + row * 128 + ((kk * 64 + g * 16) ^ ((row & 7) << 4)));
      }
#pragma unroll
      for (int nt = 0; nt < 4; ++nt) {
        const int row = wn + nt * 16 + l15;
        bf_[nt] = *(const short8*)(Bs + row * 128 + ((kk * 64 + g * 16) ^ ((row & 7) << 4)));
      }
#pragma unroll
      for (int mt = 0; mt < 4; ++mt)
#pragma unroll
        for (int nt = 0; nt < 4; ++nt)
          acc[mt][nt] = __builtin_amdgcn_mfma_f32_16x16x32_bf16(af[mt], bf_[nt], acc[mt][nt], 0, 0, 0);
    }
  }

  float bv4[4];
#pragma unroll
  for (int nt = 0; nt < 4; ++nt) bv4[nt] = bias[n0 + wn + nt * 16 + l15];

  if (t < 2) {
    // Q/K epilogue: direct scatter (verified path)
#pragma unroll
    for (int mt = 0; mt < 4; ++mt) {
#pragma unroll
      for (int nt = 0; nt < 4; ++nt) {
        const int feat = n0 + wn + nt * 16 + l15;
        const int h = feat >> 6, d = feat & 63;
#pragma unroll
        for (int r = 0; r < 4; ++r) {
          const int token = m0 + wm + mt * 16 + g * 4 + r;
          const int b = token >> 11, s = token & 2047;
          const float val = acc[mt][nt][r] + bv4[nt];
          const __hip_bfloat16 hb = __float2bfloat16(val);
          if (t == 0) Qb[((size_t)(b * 16 + h) * 2048 + s) * 64 + d] = hb;
          else        Kb[((size_t)(b * 16 + h) * 2048 + s) * 64 + d] = hb;
        }
      }
    }
  } else {
    // V epilogue: LDS transpose -> coalesced stores, NATURAL key order (r7-verified)
    __hip_bfloat16* T2 = (__hip_bfloat16*)smem;
    const int bb = m0 >> 11;
    const int s0 = m0 & 2047;
#pragma unroll
    for (int p = 0; p < 2; ++p) {
      __syncthreads();
      if ((w >> 1) == p) {
#pragma unroll
        for (int mt = 0; mt < 4; ++mt)
#pragma unroll
          for (int nt = 0; nt < 4; ++nt) {
            const int feat = wn + nt * 16 + l15;
#pragma unroll
            for (int r = 0; r < 4; ++r) {
              const int tok = mt * 16 + g * 4 + r;
              T2[feat * 64 + (tok ^ ((feat & 7) << 3))] =
                  __float2bfloat16(acc[mt][nt][r] + bv4[nt]);
            }
          }
      }
      __syncthreads();
#pragma unroll
      for (int sw = 0; sw < 4; ++sw) {
        const int row = sw * 32 + (tid >> 3);
        const int c = tid & 7;
        const short8 vchunk = *(const short8*)(smem + row * 128 + 16 * (c ^ (row & 7)));
        const int gfeat = n0 + row;
        const int hh = gfeat >> 6, dd = gfeat & 63;
        *(short8*)(Vt + ((size_t)((bb * 16 + hh) * 64 + dd)) * 2048 + s0 + p * 64 + c * 8) = vchunk;
      }
    }
  }
}

// ---------------- kernel 3: flash attention (KVBLK=128, r16 inner x2) ----------
// 512 blocks (XCD-swizzled) x 256 threads (4 waves x 32 q). 16 bodies of 128 keys,
// each = two r16-verified 64-key halves. Double-buffered K+V (64 KB), stage-next
// at body start (r13-proven sync: __syncthreads at body end). Mask-bias loads for
// both halves issued FIRST so their wait leaves the prefetch in flight.
__global__ __launch_bounds__(256, 2) void k_attn(
    const __hip_bfloat16* __restrict__ Qb, const __hip_bfloat16* __restrict__ Kb,
    const __hip_bfloat16* __restrict__ Vt, const float* __restrict__ bias2,
    float* __restrict__ out) {
  __shared__ char smem[2][32768];           // per buf: K [2 halves][64 slots][128B swz],
                                            //          V at +16384, same shape
  const int orig = blockIdx.x;
  const int swz = (orig & 7) * 64 + (orig >> 3);   // bijective; 4 heads per XCD
  const int bh = swz >> 4, qb = swz & 15;
  const int b = bh >> 4, h = bh & 15;
  const int tid = threadIdx.x, w = tid >> 6, lane = tid & 63;
  const int g = lane >> 4, l15 = lane & 15;
  const char* Qc = (const char*)(Qb + (size_t)bh * 131072);
  const char* Kc = (const char*)(Kb + (size_t)bh * 131072);
  const char* Vc = (const char*)(Vt + (size_t)bh * 131072);

  const int l8 = lane >> 3, l7 = lane & 7;
  const int vswz = ((l7 ^ l8) << 4);        // pre-swizzled global 16B slot in 128B row

  // Q B-fragments for the wave's TWO q-tiles
  short8 aq[2][2];
  const int arow0 = qb * 128 + w * 32 + l15;
#pragma unroll
  for (int qt = 0; qt < 2; ++qt)
#pragma unroll
    for (int kc = 0; kc < 2; ++kc)
      aq[qt][kc] = *(const short8*)(Qc + (size_t)(arow0 + qt * 16) * 128 + kc * 64 + g * 16);

  f32x4 oaccA[4], oaccB[4];
#pragma unroll
  for (int i = 0; i < 4; ++i) {
    oaccA[i] = (f32x4){0.f, 0.f, 0.f, 0.f};
    oaccB[i] = (f32x4){0.f, 0.f, 0.f, 0.f};
  }
  f32x4 laccA = (f32x4){0.f, 0.f, 0.f, 0.f};
  f32x4 laccB = (f32x4){0.f, 0.f, 0.f, 0.f};
  const short8 ones8 = {(short)0x3F80, (short)0x3F80, (short)0x3F80, (short)0x3F80,
                        (short)0x3F80, (short)0x3F80, (short)0x3F80, (short)0x3F80};

  // staging pointers: wave w fills chunks (half hj=j>>1, ch2=w*2+(j&1))
  const char* kst[4];
  const char* vst[4];
  int ldst[4];                              // LDS chunk offsets (buf-relative)
#pragma unroll
  for (int j = 0; j < 4; ++j) {
    const int hj = j >> 1, ch2 = w * 2 + (j & 1);
    const int s = ch2 * 8 + l8;
    const int nt0 = s >> 4, gg = (s >> 2) & 3, rr = s & 3;
    const int kap = (nt0 >> 1) * 32 + gg * 8 + ((nt0 & 1) << 2) + rr;  // permuted key
    kst[j] = Kc + (size_t)(hj * 64 + kap) * 128 + vswz;
    vst[j] = Vc + (size_t)s * 4096 + hj * 128 + vswz;
    ldst[j] = hj * 8192 + ch2 * 1024;
  }

  // prologue: stage body 0 into buf 0
#pragma unroll
  for (int j = 0; j < 4; ++j) {
    gload16(kst[j], smem[0] + ldst[j]);
    gload16(vst[j], smem[0] + 16384 + ldst[j]);
    kst[j] += 16384;
    vst[j] += 256;
  }
  __syncthreads();

  const float* mbp = bias2 + b * 2048;
  int cur = 0;
  for (int t = 0; t < 16; ++t) {
    // mask-bias for both halves FIRST (oldest in vmcnt order)
    float4 mb[8];
#pragma unroll
    for (int i = 0; i < 8; ++i)
      mb[i] = *(const float4*)(mbp + (i >> 2) * 64 + (((i >> 1) & 1) << 5) + ((i & 1) << 2) + g * 8);
    mbp += 128;
    __builtin_amdgcn_sched_barrier(0);
    if (t < 15) {
#pragma unroll
      for (int j = 0; j < 4; ++j) {
        gload16(kst[j], smem[cur ^ 1] + ldst[j]);
        gload16(vst[j], smem[cur ^ 1] + 16384 + ldst[j]);
        kst[j] += 16384;
        vst[j] += 256;
      }
    }
    const char* Kbs = smem[cur];
    const char* Vbs = smem[cur] + 16384;
#pragma unroll
    for (int hh = 0; hh < 2; ++hh) {
      const char* Kh = Kbs + hh * 8192;
      const char* Vh = Vbs + hh * 8192;
      f32x4 sA[4], sB[4];
      __builtin_amdgcn_s_setprio(1);
#pragma unroll
      for (int nt = 0; nt < 4; ++nt) {
        const int key = nt * 16 + l15;
        const int ksw = (key & 7) << 4;
        const short8 kf0 = *(const short8*)(Kh + key * 128 + ((g * 16) ^ ksw));
        const short8 kf1 = *(const short8*)(Kh + key * 128 + ((64 + g * 16) ^ ksw));
        f32x4 z = (f32x4){0.f, 0.f, 0.f, 0.f};
        sA[nt] = __builtin_amdgcn_mfma_f32_16x16x32_bf16(kf0, aq[0][0], z, 0, 0, 0);
        sA[nt] = __builtin_amdgcn_mfma_f32_16x16x32_bf16(kf1, aq[0][1], sA[nt], 0, 0, 0);
        sB[nt] = __builtin_amdgcn_mfma_f32_16x16x32_bf16(kf0, aq[1][0], z, 0, 0, 0);
        sB[nt] = __builtin_amdgcn_mfma_f32_16x16x32_bf16(kf1, aq[1][1], sB[nt], 0, 0, 0);
      }
      __builtin_amdgcn_s_setprio(0);
      short8 pbA[2], pbB[2];
#pragma unroll
      for (int c = 0; c < 2; ++c) {
        union { short8 s8; __hip_bfloat16 hhx[8]; } pa, pb;
#pragma unroll
        for (int e = 0; e < 8; ++e) {
          const int nt = 2 * c + (e >> 2);
          const float4 m4 = mb[hh * 4 + nt];
          const float mbe = (e & 3) == 0 ? m4.x : (e & 3) == 1 ? m4.y :
                            (e & 3) == 2 ? m4.z : m4.w;
          pa.hhx[e] = __float2bfloat16(EXP2F(fmaf(sA[nt][e & 3], SC_L2E, mbe)));
          pb.hhx[e] = __float2bfloat16(EXP2F(fmaf(sB[nt][e & 3], SC_L2E, mbe)));
        }
        pbA[c] = pa.s8; pbB[c] = pb.s8;
      }
      __builtin_amdgcn_s_setprio(1);
      laccA = __builtin_amdgcn_mfma_f32_16x16x32_bf16(ones8, pbA[0], laccA, 0, 0, 0);
      laccA = __builtin_amdgcn_mfma_f32_16x16x32_bf16(ones8, pbA[1], laccA, 0, 0, 0);
      laccB = __builtin_amdgcn_mfma_f32_16x16x32_bf16(ones8, pbB[0], laccB, 0, 0, 0);
      laccB = __builtin_amdgcn_mfma_f32_16x16x32_bf16(ones8, pbB[1], laccB, 0, 0, 0);
#pragma unroll
      for (int dt = 0; dt < 4; ++dt) {
        const int d = dt * 16 + l15;
        const int sw2 = (d & 7) << 4;
        const short8 v0 = *(const short8*)(Vh + d * 128 + ((g * 16) ^ sw2));
        const short8 v1 = *(const short8*)(Vh + d * 128 + ((64 + g * 16) ^ sw2));
        f32x4 oa = oaccA[dt], ob = oaccB[dt];
        oa = __builtin_amdgcn_mfma_f32_16x16x32_bf16(v0, pbA[0], oa, 0, 0, 0);
        oa = __builtin_amdgcn_mfma_f32_16x16x32_bf16(v1, pbA[1], oa, 0, 0, 0);
        ob = __builtin_amdgcn_mfma_f32_16x16x32_bf16(v0, pbB[0], ob, 0, 0, 0);
        ob = __builtin_amdgcn_mfma_f32_16x16x32_bf16(v1, pbB[1], ob, 0, 0, 0);
        oaccA[dt] = oa; oaccB[dt] = ob;
      }
      __builtin_amdgcn_s_setprio(0);
    }
    __syncthreads();
    cur ^= 1;
  }

  // epilogue: per q-tile, lacc rows all equal the full denominator
  const float rlA = 1.0f / laccA[0];
  const float rlB = 1.0f / laccB[0];
  float* orowA = out + ((size_t)(b * 2048 + arow0)) * 1024 + h * 64;
  float* orowB = orowA + 16 * 1024;
#pragma unroll
  for (int dt = 0; dt < 4; ++dt) {
    float4 stA, stB;
    stA.x = oaccA[dt][0] * rlA; stA.y = oaccA[dt][1] * rlA;
    stA.z = oaccA[dt][2] * rlA; stA.w = oaccA[dt][3] * rlA;
    stB.x = oaccB[dt][0] * rlB; stB.y = oaccB[dt][1] * rlB;
    stB.z = oaccB[dt][2] * rlB; stB.w = oaccB[dt][3] * rlB;
    *(float4*)(orowA + dt * 16 + g * 4) = stA;
    *(float4*)(orowB + dt * 16 + g * 4) = stB;
  }
}

// ---------------- launcher ----------------
extern "C" void kernel_launch(void* const* d_in, const int* in_sizes, int n_in,
                              void* d_out, int out_size, void* d_ws, size_t ws_size,
                              hipStream_t stream) {
  const float* q   = (const float*)d_in[0];
  const float* k   = (const float*)d_in[1];
  const float* v   = (const float*)d_in[2];
  const int* mask  = (const int*)d_in[3];
  const float* Wq  = (const float*)d_in[4];
  const float* bq  = (const float*)d_in[5];
  const float* Wk  = (const float*)d_in[6];
  const float* bk  = (const float*)d_in[7];
  const float* Wv  = (const float*)d_in[8];
  const float* bv  = (const float*)d_in[9];
  float* out = (float*)d_out;
  char* ws = (char*)d_ws;
  __hip_bfloat16* Xb = (__hip_bfloat16*)(ws);
  __hip_bfloat16* Wt = (__hip_bfloat16*)(ws + 25165824);
  __hip_bfloat16* Qb = (__hip_bfloat16*)(ws + 31457280);
  __hip_bfloat16* Kb = (__hip_bfloat16*)(ws + 39845888);
  __hip_bfloat16* Vt = (__hip_bfloat16*)(ws + 48234496);
  float* bias2      = (float*)(ws + 56623104);   // 4096 floats

  k_cvt<<<dim3(6912), dim3(256), 0, stream>>>(q, k, v, Xb, Wq, Wk, Wv, Wt, mask, bias2);
  k_proj<<<dim3(768), dim3(256), 0, stream>>>(Xb, Wt, bq, bk, bv, Qb, Kb, Vt);
  k_attn<<<dim3(512), dim3(256), 0, stream>>>(Qb, Kb, Vt, bias2, out);
}

// Round 19
// 94.804 us; speedup vs baseline: 1.3992x; 1.0573x over previous
//
#include <hip/hip_runtime.h>
#include <hip/hip_bf16.h>

typedef __attribute__((ext_vector_type(8))) short short8;
typedef __attribute__((ext_vector_type(4))) float f32x4;

#define SC_L2E 0.4561727848849353f          // (1/sqrt(10)) * log2(e)

#if __has_builtin(__builtin_amdgcn_exp2f)
#define EXP2F __builtin_amdgcn_exp2f
#else
#define EXP2F exp2f
#endif

static __device__ __forceinline__ void gload16(const void* g, void* l) {
  __builtin_amdgcn_global_load_lds((const __attribute__((address_space(1))) void*)g,
                                   (__attribute__((address_space(3))) void*)l, 16, 0, 0);
}

// ---------------- kernel 1: fused converts (r9-verified) ----------------
__global__ void k_cvt(const float* __restrict__ q, const float* __restrict__ kk,
                      const float* __restrict__ v, __hip_bfloat16* __restrict__ xb,
                      const float* __restrict__ Wq, const float* __restrict__ Wk,
                      const float* __restrict__ Wv, __hip_bfloat16* __restrict__ wt,
                      const int* __restrict__ mask, float* __restrict__ bias2) {
  __shared__ float T[64][65];
  if (blockIdx.x < 6144) {
    const size_t i = ((size_t)blockIdx.x * 256 + threadIdx.x) * 8;
    const int t = (int)(i >> 22);               // 4194304 elements per tensor
    const float* src = (t == 0) ? q : (t == 1) ? kk : v;
    const size_t off = i & 4194303u;
    float4 f0 = *(const float4*)(src + off);
    float4 f1 = *(const float4*)(src + off + 4);
    union { short8 s; __hip_bfloat16 h[8]; } u;
    u.h[0] = __float2bfloat16(f0.x); u.h[1] = __float2bfloat16(f0.y);
    u.h[2] = __float2bfloat16(f0.z); u.h[3] = __float2bfloat16(f0.w);
    u.h[4] = __float2bfloat16(f1.x); u.h[5] = __float2bfloat16(f1.y);
    u.h[6] = __float2bfloat16(f1.z); u.h[7] = __float2bfloat16(f1.w);
    *(short8*)((char*)xb + i * 2) = u.s;
    return;
  }
  const int idx2 = blockIdx.x - 6144;           // 0..767
  const int z = idx2 >> 8;                      // 0..2
  const int r2 = idx2 & 255;
  const int bxi = r2 & 15, byi = r2 >> 4;
  if (z == 0 && byi == 0) {
    const int idx = bxi * 256 + threadIdx.x;
    bias2[idx] = mask[idx] ? -12.0f : -1e30f;   // static shift M=12 folded in
  }
  const float* W = (z == 0) ? Wq : (z == 1) ? Wk : Wv;
  __hip_bfloat16* Wd = wt + (size_t)z * 1048576;
  const int n0 = bxi * 64, k0 = byi * 64;
  const int tx = threadIdx.x & 63, ty = threadIdx.x >> 6;
#pragma unroll
  for (int r = 0; r < 16; ++r)
    T[ty + r * 4][tx] = W[(size_t)(k0 + ty + r * 4) * 1024 + n0 + tx];
  __syncthreads();
#pragma unroll
  for (int r = 0; r < 16; ++r)
    Wd[(size_t)(n0 + ty + r * 4) * 1024 + k0 + tx] = __float2bfloat16(T[tx][ty + r * 4]);
}

// ---------------- kernel 2: projection GEMM (BK=128: 8 bodies, half the drains) -
__global__ __launch_bounds__(256) void k_proj(
    const __hip_bfloat16* __restrict__ xb, const __hip_bfloat16* __restrict__ wt,
    const float* __restrict__ bq, const float* __restrict__ bk, const float* __restrict__ bv,
    __hip_bfloat16* __restrict__ Qb, __hip_bfloat16* __restrict__ Kb,
    __hip_bfloat16* __restrict__ Vt) {
  __shared__ char smem[65536];
  char* As = smem;            // [128 rows][128 bf16] = 256 B rows, 32 KB
  char* Bs = smem + 32768;
  const int orig = blockIdx.x;
  const int xcd = orig & 7, idx = orig >> 3;    // idx 0..95
  const int by = xcd * 4 + (idx & 3);           // 0..31
  const int bx = (idx >> 2) & 7;                // 0..7
  const int t = idx >> 5;                       // 0..2
  const char* X = (const char*)(xb + (size_t)t * 4194304);
  const char* W = (const char*)(wt + (size_t)t * 1048576);
  const float* bias = (t == 0) ? bq : (t == 1) ? bk : bv;
  const int m0 = by * 128, n0 = bx * 128;
  const int tid = threadIdx.x, w = tid >> 6, lane = tid & 63;
  const int l15 = lane & 15, g = lane >> 4;
  const int wm = (w >> 1) * 64, wn = (w & 1) * 64;
  // staging geometry: 32 chunks/matrix, 4 rows/chunk, 16 lanes/row
  const int srow_in = lane >> 4;                // row within chunk
  const int sbyte_base = (l15 << 4);            // byte within 256B row (pre-XOR)
  f32x4 acc[4][4];
#pragma unroll
  for (int i = 0; i < 4; ++i)
#pragma unroll
    for (int j = 0; j < 4; ++j) acc[i][j] = (f32x4){0.f, 0.f, 0.f, 0.f};

  for (int k0 = 0; k0 < 4096; k0 += 512) {      // 8 K-steps of 128 elems (bytes)
    __syncthreads();
#pragma unroll
    for (int j = 0; j < 8; ++j) {
      const int ch = w * 8 + j;                 // 32 chunks of 4 rows
      const int row = ch * 4 + srow_in;
      const int sb = sbyte_base ^ ((row & 7) << 4);
      gload16(X + (size_t)(m0 + row) * 2048 + (k0 >> 1) + sb, As + ch * 1024);
      gload16(W + (size_t)(n0 + row) * 2048 + (k0 >> 1) + sb, Bs + ch * 1024);
    }
    __syncthreads();
#pragma unroll
    for (int kk = 0; kk < 4; ++kk) {
      short8 af[4], bf_[4];
#pragma unroll
      for (int mt = 0; mt < 4; ++mt) {
        const int row = wm + mt * 16 + l15;
        af[mt] = *(const short8*)(As + row * 256 + ((kk * 64 + g * 16) ^ ((row & 7) << 4)));
      }
#pragma unroll
      for (int nt = 0; nt < 4; ++nt) {
        const int row = wn + nt * 16 + l15;
        bf_[nt] = *(const short8*)(Bs + row * 256 + ((kk * 64 + g * 16) ^ ((row & 7) << 4)));
      }
#pragma unroll
      for (int mt = 0; mt < 4; ++mt)
#pragma unroll
        for (int nt = 0; nt < 4; ++nt)
          acc[mt][nt] = __builtin_amdgcn_mfma_f32_16x16x32_bf16(af[mt], bf_[nt], acc[mt][nt], 0, 0, 0);
    }
  }

  float bv4[4];
#pragma unroll
  for (int nt = 0; nt < 4; ++nt) bv4[nt] = bias[n0 + wn + nt * 16 + l15];

  if (t < 2) {
    // Q/K epilogue: direct scatter (verified path)
#pragma unroll
    for (int mt = 0; mt < 4; ++mt) {
#pragma unroll
      for (int nt = 0; nt < 4; ++nt) {
        const int feat = n0 + wn + nt * 16 + l15;
        const int h = feat >> 6, d = feat & 63;
#pragma unroll
        for (int r = 0; r < 4; ++r) {
          const int token = m0 + wm + mt * 16 + g * 4 + r;
          const int b = token >> 11, s = token & 2047;
          const float val = acc[mt][nt][r] + bv4[nt];
          const __hip_bfloat16 hb = __float2bfloat16(val);
          if (t == 0) Qb[((size_t)(b * 16 + h) * 2048 + s) * 64 + d] = hb;
          else        Kb[((size_t)(b * 16 + h) * 2048 + s) * 64 + d] = hb;
        }
      }
    }
  } else {
    // V epilogue: LDS transpose -> coalesced stores, NATURAL key order (r7-verified)
    __hip_bfloat16* T2 = (__hip_bfloat16*)smem;
    const int bb = m0 >> 11;
    const int s0 = m0 & 2047;
#pragma unroll
    for (int p = 0; p < 2; ++p) {
      __syncthreads();
      if ((w >> 1) == p) {
#pragma unroll
        for (int mt = 0; mt < 4; ++mt)
#pragma unroll
          for (int nt = 0; nt < 4; ++nt) {
            const int feat = wn + nt * 16 + l15;
#pragma unroll
            for (int r = 0; r < 4; ++r) {
              const int tok = mt * 16 + g * 4 + r;
              T2[feat * 64 + (tok ^ ((feat & 7) << 3))] =
                  __float2bfloat16(acc[mt][nt][r] + bv4[nt]);
            }
          }
      }
      __syncthreads();
#pragma unroll
      for (int sw = 0; sw < 4; ++sw) {
        const int row = sw * 32 + (tid >> 3);
        const int c = tid & 7;
        const short8 vchunk = *(const short8*)(smem + row * 128 + 16 * (c ^ (row & 7)));
        const int gfeat = n0 + row;
        const int hh = gfeat >> 6, dd = gfeat & 63;
        *(short8*)(Vt + ((size_t)((bb * 16 + hh) * 64 + dd)) * 2048 + s0 + p * 64 + c * 8) = vchunk;
      }
    }
  }
}

// ---------------- kernel 3: flash attention (r18-verified, KVBLK=128) ----------
__global__ __launch_bounds__(256, 2) void k_attn(
    const __hip_bfloat16* __restrict__ Qb, const __hip_bfloat16* __restrict__ Kb,
    const __hip_bfloat16* __restrict__ Vt, const float* __restrict__ bias2,
    float* __restrict__ out) {
  __shared__ char smem[2][32768];           // per buf: K [2 halves][64 slots][128B swz],
                                            //          V at +16384, same shape
  const int orig = blockIdx.x;
  const int swz = (orig & 7) * 64 + (orig >> 3);   // bijective; 4 heads per XCD
  const int bh = swz >> 4, qb = swz & 15;
  const int b = bh >> 4, h = bh & 15;
  const int tid = threadIdx.x, w = tid >> 6, lane = tid & 63;
  const int g = lane >> 4, l15 = lane & 15;
  const char* Qc = (const char*)(Qb + (size_t)bh * 131072);
  const char* Kc = (const char*)(Kb + (size_t)bh * 131072);
  const char* Vc = (const char*)(Vt + (size_t)bh * 131072);

  const int l8 = lane >> 3, l7 = lane & 7;
  const int vswz = ((l7 ^ l8) << 4);        // pre-swizzled global 16B slot in 128B row

  // Q B-fragments for the wave's TWO q-tiles
  short8 aq[2][2];
  const int arow0 = qb * 128 + w * 32 + l15;
#pragma unroll
  for (int qt = 0; qt < 2; ++qt)
#pragma unroll
    for (int kc = 0; kc < 2; ++kc)
      aq[qt][kc] = *(const short8*)(Qc + (size_t)(arow0 + qt * 16) * 128 + kc * 64 + g * 16);

  f32x4 oaccA[4], oaccB[4];
#pragma unroll
  for (int i = 0; i < 4; ++i) {
    oaccA[i] = (f32x4){0.f, 0.f, 0.f, 0.f};
    oaccB[i] = (f32x4){0.f, 0.f, 0.f, 0.f};
  }
  f32x4 laccA = (f32x4){0.f, 0.f, 0.f, 0.f};
  f32x4 laccB = (f32x4){0.f, 0.f, 0.f, 0.f};
  const short8 ones8 = {(short)0x3F80, (short)0x3F80, (short)0x3F80, (short)0x3F80,
                        (short)0x3F80, (short)0x3F80, (short)0x3F80, (short)0x3F80};

  // staging pointers: wave w fills chunks (half hj=j>>1, ch2=w*2+(j&1))
  const char* kst[4];
  const char* vst[4];
  int ldst[4];                              // LDS chunk offsets (buf-relative)
#pragma unroll
  for (int j = 0; j < 4; ++j) {
    const int hj = j >> 1, ch2 = w * 2 + (j & 1);
    const int s = ch2 * 8 + l8;
    const int nt0 = s >> 4, gg = (s >> 2) & 3, rr = s & 3;
    const int kap = (nt0 >> 1) * 32 + gg * 8 + ((nt0 & 1) << 2) + rr;  // permuted key
    kst[j] = Kc + (size_t)(hj * 64 + kap) * 128 + vswz;
    vst[j] = Vc + (size_t)s * 4096 + hj * 128 + vswz;
    ldst[j] = hj * 8192 + ch2 * 1024;
  }

  // prologue: stage body 0 into buf 0
#pragma unroll
  for (int j = 0; j < 4; ++j) {
    gload16(kst[j], smem[0] + ldst[j]);
    gload16(vst[j], smem[0] + 16384 + ldst[j]);
    kst[j] += 16384;
    vst[j] += 256;
  }
  __syncthreads();

  const float* mbp = bias2 + b * 2048;
  int cur = 0;
  for (int t = 0; t < 16; ++t) {
    // mask-bias for both halves FIRST (oldest in vmcnt order)
    float4 mb[8];
#pragma unroll
    for (int i = 0; i < 8; ++i)
      mb[i] = *(const float4*)(mbp + (i >> 2) * 64 + (((i >> 1) & 1) << 5) + ((i & 1) << 2) + g * 8);
    mbp += 128;
    __builtin_amdgcn_sched_barrier(0);
    if (t < 15) {
#pragma unroll
      for (int j = 0; j < 4; ++j) {
        gload16(kst[j], smem[cur ^ 1] + ldst[j]);
        gload16(vst[j], smem[cur ^ 1] + 16384 + ldst[j]);
        kst[j] += 16384;
        vst[j] += 256;
      }
    }
    const char* Kbs = smem[cur];
    const char* Vbs = smem[cur] + 16384;
#pragma unroll
    for (int hh = 0; hh < 2; ++hh) {
      const char* Kh = Kbs + hh * 8192;
      const char* Vh = Vbs + hh * 8192;
      f32x4 sA[4], sB[4];
      __builtin_amdgcn_s_setprio(1);
#pragma unroll
      for (int nt = 0; nt < 4; ++nt) {
        const int key = nt * 16 + l15;
        const int ksw = (key & 7) << 4;
        const short8 kf0 = *(const short8*)(Kh + key * 128 + ((g * 16) ^ ksw));
        const short8 kf1 = *(const short8*)(Kh + key * 128 + ((64 + g * 16) ^ ksw));
        f32x4 z = (f32x4){0.f, 0.f, 0.f, 0.f};
        sA[nt] = __builtin_amdgcn_mfma_f32_16x16x32_bf16(kf0, aq[0][0], z, 0, 0, 0);
        sA[nt] = __builtin_amdgcn_mfma_f32_16x16x32_bf16(kf1, aq[0][1], sA[nt], 0, 0, 0);
        sB[nt] = __builtin_amdgcn_mfma_f32_16x16x32_bf16(kf0, aq[1][0], z, 0, 0, 0);
        sB[nt] = __builtin_amdgcn_mfma_f32_16x16x32_bf16(kf1, aq[1][1], sB[nt], 0, 0, 0);
      }
      __builtin_amdgcn_s_setprio(0);
      short8 pbA[2], pbB[2];
#pragma unroll
      for (int c = 0; c < 2; ++c) {
        union { short8 s8; __hip_bfloat16 hhx[8]; } pa, pb;
#pragma unroll
        for (int e = 0; e < 8; ++e) {
          const int nt = 2 * c + (e >> 2);
          const float4 m4 = mb[hh * 4 + nt];
          const float mbe = (e & 3) == 0 ? m4.x : (e & 3) == 1 ? m4.y :
                            (e & 3) == 2 ? m4.z : m4.w;
          pa.hhx[e] = __float2bfloat16(EXP2F(fmaf(sA[nt][e & 3], SC_L2E, mbe)));
          pb.hhx[e] = __float2bfloat16(EXP2F(fmaf(sB[nt][e & 3], SC_L2E, mbe)));
        }
        pbA[c] = pa.s8; pbB[c] = pb.s8;
      }
      __builtin_amdgcn_s_setprio(1);
      laccA = __builtin_amdgcn_mfma_f32_16x16x32_bf16(ones8, pbA[0], laccA, 0, 0, 0);
      laccA = __builtin_amdgcn_mfma_f32_16x16x32_bf16(ones8, pbA[1], laccA, 0, 0, 0);
      laccB = __builtin_amdgcn_mfma_f32_16x16x32_bf16(ones8, pbB[0], laccB, 0, 0, 0);
      laccB = __builtin_amdgcn_mfma_f32_16x16x32_bf16(ones8, pbB[1], laccB, 0, 0, 0);
#pragma unroll
      for (int dt = 0; dt < 4; ++dt) {
        const int d = dt * 16 + l15;
        const int sw2 = (d & 7) << 4;
        const short8 v0 = *(const short8*)(Vh + d * 128 + ((g * 16) ^ sw2));
        const short8 v1 = *(const short8*)(Vh + d * 128 + ((64 + g * 16) ^ sw2));
        f32x4 oa = oaccA[dt], ob = oaccB[dt];
        oa = __builtin_amdgcn_mfma_f32_16x16x32_bf16(v0, pbA[0], oa, 0, 0, 0);
        oa = __builtin_amdgcn_mfma_f32_16x16x32_bf16(v1, pbA[1], oa, 0, 0, 0);
        ob = __builtin_amdgcn_mfma_f32_16x16x32_bf16(v0, pbB[0], ob, 0, 0, 0);
        ob = __builtin_amdgcn_mfma_f32_16x16x32_bf16(v1, pbB[1], ob, 0, 0, 0);
        oaccA[dt] = oa; oaccB[dt] = ob;
      }
      __builtin_amdgcn_s_setprio(0);
    }
    __syncthreads();
    cur ^= 1;
  }

  // epilogue: per q-tile, lacc rows all equal the full denominator
  const float rlA = 1.0f / laccA[0];
  const float rlB = 1.0f / laccB[0];
  float* orowA = out + ((size_t)(b * 2048 + arow0)) * 1024 + h * 64;
  float* orowB = orowA + 16 * 1024;
#pragma unroll
  for (int dt = 0; dt < 4; ++dt) {
    float4 stA, stB;
    stA.x = oaccA[dt][0] * rlA; stA.y = oaccA[dt][1] * rlA;
    stA.z = oaccA[dt][2] * rlA; stA.w = oaccA[dt][3] * rlA;
    stB.x = oaccB[dt][0] * rlB; stB.y = oaccB[dt][1] * rlB;
    stB.z = oaccB[dt][2] * rlB; stB.w = oaccB[dt][3] * rlB;
    *(float4*)(orowA + dt * 16 + g * 4) = stA;
    *(float4*)(orowB + dt * 16 + g * 4) = stB;
  }
}

// ---------------- launcher ----------------
extern "C" void kernel_launch(void* const* d_in, const int* in_sizes, int n_in,
                              void* d_out, int out_size, void* d_ws, size_t ws_size,
                              hipStream_t stream) {
  const float* q   = (const float*)d_in[0];
  const float* k   = (const float*)d_in[1];
  const float* v   = (const float*)d_in[2];
  const int* mask  = (const int*)d_in[3];
  const float* Wq  = (const float*)d_in[4];
  const float* bq  = (const float*)d_in[5];
  const float* Wk  = (const float*)d_in[6];
  const float* bk  = (const float*)d_in[7];
  const float* Wv  = (const float*)d_in[8];
  const float* bv  = (const float*)d_in[9];
  float* out = (float*)d_out;
  char* ws = (char*)d_ws;
  __hip_bfloat16* Xb = (__hip_bfloat16*)(ws);
  __hip_bfloat16* Wt = (__hip_bfloat16*)(ws + 25165824);
  __hip_bfloat16* Qb = (__hip_bfloat16*)(ws + 31457280);
  __hip_bfloat16* Kb = (__hip_bfloat16*)(ws + 39845888);
  __hip_bfloat16* Vt = (__hip_bfloat16*)(ws + 48234496);
  float* bias2      = (float*)(ws + 56623104);   // 4096 floats

  k_cvt<<<dim3(6912), dim3(256), 0, stream>>>(q, k, v, Xb, Wq, Wk, Wv, Wt, mask, bias2);
  k_proj<<<dim3(768), dim3(256), 0, stream>>>(Xb, Wt, bq, bk, bv, Qb, Kb, Vt);
  k_attn<<<dim3(512), dim3(256), 0, stream>>>(Qb, Kb, Vt, bias2, out);
}

// Round 20
// 91.368 us; speedup vs baseline: 1.4518x; 1.0376x over previous
//
#include <hip/hip_runtime.h>
#include <hip/hip_bf16.h>

typedef __attribute__((ext_vector_type(8))) short short8;
typedef __attribute__((ext_vector_type(4))) float f32x4;

#define SC_L2E 0.4561727848849353f          // (1/sqrt(10)) * log2(e)

#if __has_builtin(__builtin_amdgcn_exp2f)
#define EXP2F __builtin_amdgcn_exp2f
#else
#define EXP2F exp2f
#endif

static __device__ __forceinline__ void gload16(const void* g, void* l) {
  __builtin_amdgcn_global_load_lds((const __attribute__((address_space(1))) void*)g,
                                   (__attribute__((address_space(3))) void*)l, 16, 0, 0);
}

// ---------------- kernel 1: fused converts (r9-verified) ----------------
__global__ void k_cvt(const float* __restrict__ q, const float* __restrict__ kk,
                      const float* __restrict__ v, __hip_bfloat16* __restrict__ xb,
                      const float* __restrict__ Wq, const float* __restrict__ Wk,
                      const float* __restrict__ Wv, __hip_bfloat16* __restrict__ wt,
                      const int* __restrict__ mask, float* __restrict__ bias2) {
  __shared__ float T[64][65];
  if (blockIdx.x < 6144) {
    const size_t i = ((size_t)blockIdx.x * 256 + threadIdx.x) * 8;
    const int t = (int)(i >> 22);               // 4194304 elements per tensor
    const float* src = (t == 0) ? q : (t == 1) ? kk : v;
    const size_t off = i & 4194303u;
    float4 f0 = *(const float4*)(src + off);
    float4 f1 = *(const float4*)(src + off + 4);
    union { short8 s; __hip_bfloat16 h[8]; } u;
    u.h[0] = __float2bfloat16(f0.x); u.h[1] = __float2bfloat16(f0.y);
    u.h[2] = __float2bfloat16(f0.z); u.h[3] = __float2bfloat16(f0.w);
    u.h[4] = __float2bfloat16(f1.x); u.h[5] = __float2bfloat16(f1.y);
    u.h[6] = __float2bfloat16(f1.z); u.h[7] = __float2bfloat16(f1.w);
    *(short8*)((char*)xb + i * 2) = u.s;
    return;
  }
  const int idx2 = blockIdx.x - 6144;           // 0..767
  const int z = idx2 >> 8;                      // 0..2
  const int r2 = idx2 & 255;
  const int bxi = r2 & 15, byi = r2 >> 4;
  if (z == 0 && byi == 0) {
    const int idx = bxi * 256 + threadIdx.x;
    bias2[idx] = mask[idx] ? -12.0f : -1e30f;   // static shift M=12 folded in
  }
  const float* W = (z == 0) ? Wq : (z == 1) ? Wk : Wv;
  __hip_bfloat16* Wd = wt + (size_t)z * 1048576;
  const int n0 = bxi * 64, k0 = byi * 64;
  const int tx = threadIdx.x & 63, ty = threadIdx.x >> 6;
#pragma unroll
  for (int r = 0; r < 16; ++r)
    T[ty + r * 4][tx] = W[(size_t)(k0 + ty + r * 4) * 1024 + n0 + tx];
  __syncthreads();
#pragma unroll
  for (int r = 0; r < 16; ++r)
    Wd[(size_t)(n0 + ty + r * 4) * 1024 + k0 + tx] = __float2bfloat16(T[tx][ty + r * 4]);
}

// ---------------- kernel 2: projection GEMM (256x128 tile, 8 waves, BK=64) -----
// 384 blocks (XCD-swizzled) x 512 threads; LDS 48KB -> fully co-resident grid
// (no tail round). Per-wave inner body byte-identical to the r12-verified BK=64
// pattern; wave grid 4m x 2n, each wave owns a 64x64 output.
__global__ __launch_bounds__(512) void k_proj(
    const __hip_bfloat16* __restrict__ xb, const __hip_bfloat16* __restrict__ wt,
    const float* __restrict__ bq, const float* __restrict__ bk, const float* __restrict__ bv,
    __hip_bfloat16* __restrict__ Qb, __hip_bfloat16* __restrict__ Kb,
    __hip_bfloat16* __restrict__ Vt) {
  __shared__ char smem[49152];
  char* As = smem;            // [256 rows][64 bf16] = 128 B rows, 32 KB
  char* Bs = smem + 32768;    // [128 rows][64 bf16] = 16 KB
  const int orig = blockIdx.x;
  const int xcd = orig & 7, idx = orig >> 3;    // idx 0..47
  const int t = idx >> 4;                       // 0..2
  const int rr2 = idx & 15;
  const int by = xcd * 2 + (rr2 & 1);           // 0..15 (m-band of 256)
  const int bx = rr2 >> 1;                      // 0..7
  const char* X = (const char*)(xb + (size_t)t * 4194304);
  const char* W = (const char*)(wt + (size_t)t * 1048576);
  const float* bias = (t == 0) ? bq : (t == 1) ? bk : bv;
  const int m0 = by * 256, n0 = bx * 128;
  const int tid = threadIdx.x, w = tid >> 6, lane = tid & 63;
  const int l15 = lane & 15, g = lane >> 4;
  const int l8 = lane >> 3, l7 = lane & 7;
  const int vswz = ((l7 ^ l8) << 4);            // pre-swizzled 16B slot in 128B row
  const int wm = (w >> 1) * 64, wn = (w & 1) * 64;
  f32x4 acc[4][4];
#pragma unroll
  for (int i = 0; i < 4; ++i)
#pragma unroll
    for (int j = 0; j < 4; ++j) acc[i][j] = (f32x4){0.f, 0.f, 0.f, 0.f};

  for (int k0 = 0; k0 < 2048; k0 += 128) {      // 16 K-steps of 64 elems
    __syncthreads();
#pragma unroll
    for (int j = 0; j < 4; ++j) {               // A: 32 chunks of 8 rows
      const int ch = w * 4 + j;
      gload16(X + (size_t)(m0 + ch * 8 + l8) * 2048 + k0 + vswz, As + ch * 1024);
    }
#pragma unroll
    for (int j = 0; j < 2; ++j) {               // B: 16 chunks of 8 rows
      const int ch = w * 2 + j;
      gload16(W + (size_t)(n0 + ch * 8 + l8) * 2048 + k0 + vswz, Bs + ch * 1024);
    }
    __syncthreads();
#pragma unroll
    for (int kk = 0; kk < 2; ++kk) {
      short8 af[4], bf_[4];
#pragma unroll
      for (int mt = 0; mt < 4; ++mt) {
        const int row = wm + mt * 16 + l15;     // 0..255
        af[mt] = *(const short8*)(As + row * 128 + ((kk * 64 + g * 16) ^ ((row & 7) << 4)));
      }
#pragma unroll
      for (int nt = 0; nt < 4; ++nt) {
        const int row = wn + nt * 16 + l15;     // 0..127
        bf_[nt] = *(const short8*)(Bs + row * 128 + ((kk * 64 + g * 16) ^ ((row & 7) << 4)));
      }
#pragma unroll
      for (int mt = 0; mt < 4; ++mt)
#pragma unroll
        for (int nt = 0; nt < 4; ++nt)
          acc[mt][nt] = __builtin_amdgcn_mfma_f32_16x16x32_bf16(af[mt], bf_[nt], acc[mt][nt], 0, 0, 0);
    }
  }

  float bv4[4];
#pragma unroll
  for (int nt = 0; nt < 4; ++nt) bv4[nt] = bias[n0 + wn + nt * 16 + l15];

  if (t < 2) {
    // Q/K epilogue: direct scatter (verified path)
#pragma unroll
    for (int mt = 0; mt < 4; ++mt) {
#pragma unroll
      for (int nt = 0; nt < 4; ++nt) {
        const int feat = n0 + wn + nt * 16 + l15;
        const int h = feat >> 6, d = feat & 63;
#pragma unroll
        for (int r = 0; r < 4; ++r) {
          const int token = m0 + wm + mt * 16 + g * 4 + r;
          const int b = token >> 11, s = token & 2047;
          const float val = acc[mt][nt][r] + bv4[nt];
          const __hip_bfloat16 hb = __float2bfloat16(val);
          if (t == 0) Qb[((size_t)(b * 16 + h) * 2048 + s) * 64 + d] = hb;
          else        Kb[((size_t)(b * 16 + h) * 2048 + s) * 64 + d] = hb;
        }
      }
    }
  } else {
    // V epilogue: 4 passes of the r7-verified 64-token LDS transpose
    __hip_bfloat16* T2 = (__hip_bfloat16*)smem;
    const int bb = m0 >> 11;                    // 256 | 2048 -> never straddles
    const int s0 = m0 & 2047;
#pragma unroll
    for (int p = 0; p < 4; ++p) {
      __syncthreads();
      if ((w >> 1) == p) {                      // 2 waves own tokens p*64..p*64+63
#pragma unroll
        for (int mt = 0; mt < 4; ++mt)
#pragma unroll
          for (int nt = 0; nt < 4; ++nt) {
            const int feat = wn + nt * 16 + l15;
#pragma unroll
            for (int r = 0; r < 4; ++r) {
              const int tok = mt * 16 + g * 4 + r;
              T2[feat * 64 + (tok ^ ((feat & 7) << 3))] =
                  __float2bfloat16(acc[mt][nt][r] + bv4[nt]);
            }
          }
      }
      __syncthreads();
#pragma unroll
      for (int sw = 0; sw < 2; ++sw) {
        const int row = sw * 64 + (tid >> 3);   // 0..127
        const int c = tid & 7;
        const short8 vchunk = *(const short8*)(smem + row * 128 + 16 * (c ^ (row & 7)));
        const int gfeat = n0 + row;
        const int hh = gfeat >> 6, dd = gfeat & 63;
        *(short8*)(Vt + ((size_t)((bb * 16 + hh) * 64 + dd)) * 2048 + s0 + p * 64 + c * 8) = vchunk;
      }
    }
  }
}

// ---------------- kernel 3: flash attention (r18-verified, KVBLK=128) ----------
__global__ __launch_bounds__(256, 2) void k_attn(
    const __hip_bfloat16* __restrict__ Qb, const __hip_bfloat16* __restrict__ Kb,
    const __hip_bfloat16* __restrict__ Vt, const float* __restrict__ bias2,
    float* __restrict__ out) {
  __shared__ char smem[2][32768];           // per buf: K [2 halves][64 slots][128B swz],
                                            //          V at +16384, same shape
  const int orig = blockIdx.x;
  const int swz = (orig & 7) * 64 + (orig >> 3);   // bijective; 4 heads per XCD
  const int bh = swz >> 4, qb = swz & 15;
  const int b = bh >> 4, h = bh & 15;
  const int tid = threadIdx.x, w = tid >> 6, lane = tid & 63;
  const int g = lane >> 4, l15 = lane & 15;
  const char* Qc = (const char*)(Qb + (size_t)bh * 131072);
  const char* Kc = (const char*)(Kb + (size_t)bh * 131072);
  const char* Vc = (const char*)(Vt + (size_t)bh * 131072);

  const int l8 = lane >> 3, l7 = lane & 7;
  const int vswz = ((l7 ^ l8) << 4);        // pre-swizzled global 16B slot in 128B row

  // Q B-fragments for the wave's TWO q-tiles
  short8 aq[2][2];
  const int arow0 = qb * 128 + w * 32 + l15;
#pragma unroll
  for (int qt = 0; qt < 2; ++qt)
#pragma unroll
    for (int kc = 0; kc < 2; ++kc)
      aq[qt][kc] = *(const short8*)(Qc + (size_t)(arow0 + qt * 16) * 128 + kc * 64 + g * 16);

  f32x4 oaccA[4], oaccB[4];
#pragma unroll
  for (int i = 0; i < 4; ++i) {
    oaccA[i] = (f32x4){0.f, 0.f, 0.f, 0.f};
    oaccB[i] = (f32x4){0.f, 0.f, 0.f, 0.f};
  }
  f32x4 laccA = (f32x4){0.f, 0.f, 0.f, 0.f};
  f32x4 laccB = (f32x4){0.f, 0.f, 0.f, 0.f};
  const short8 ones8 = {(short)0x3F80, (short)0x3F80, (short)0x3F80, (short)0x3F80,
                        (short)0x3F80, (short)0x3F80, (short)0x3F80, (short)0x3F80};

  // staging pointers: wave w fills chunks (half hj=j>>1, ch2=w*2+(j&1))
  const char* kst[4];
  const char* vst[4];
  int ldst[4];                              // LDS chunk offsets (buf-relative)
#pragma unroll
  for (int j = 0; j < 4; ++j) {
    const int hj = j >> 1, ch2 = w * 2 + (j & 1);
    const int s = ch2 * 8 + l8;
    const int nt0 = s >> 4, gg = (s >> 2) & 3, rr = s & 3;
    const int kap = (nt0 >> 1) * 32 + gg * 8 + ((nt0 & 1) << 2) + rr;  // permuted key
    kst[j] = Kc + (size_t)(hj * 64 + kap) * 128 + vswz;
    vst[j] = Vc + (size_t)s * 4096 + hj * 128 + vswz;
    ldst[j] = hj * 8192 + ch2 * 1024;
  }

  // prologue: stage body 0 into buf 0
#pragma unroll
  for (int j = 0; j < 4; ++j) {
    gload16(kst[j], smem[0] + ldst[j]);
    gload16(vst[j], smem[0] + 16384 + ldst[j]);
    kst[j] += 16384;
    vst[j] += 256;
  }
  __syncthreads();

  const float* mbp = bias2 + b * 2048;
  int cur = 0;
  for (int t = 0; t < 16; ++t) {
    // mask-bias for both halves FIRST (oldest in vmcnt order)
    float4 mb[8];
#pragma unroll
    for (int i = 0; i < 8; ++i)
      mb[i] = *(const float4*)(mbp + (i >> 2) * 64 + (((i >> 1) & 1) << 5) + ((i & 1) << 2) + g * 8);
    mbp += 128;
    __builtin_amdgcn_sched_barrier(0);
    if (t < 15) {
#pragma unroll
      for (int j = 0; j < 4; ++j) {
        gload16(kst[j], smem[cur ^ 1] + ldst[j]);
        gload16(vst[j], smem[cur ^ 1] + 16384 + ldst[j]);
        kst[j] += 16384;
        vst[j] += 256;
      }
    }
    const char* Kbs = smem[cur];
    const char* Vbs = smem[cur] + 16384;
#pragma unroll
    for (int hh = 0; hh < 2; ++hh) {
      const char* Kh = Kbs + hh * 8192;
      const char* Vh = Vbs + hh * 8192;
      f32x4 sA[4], sB[4];
      __builtin_amdgcn_s_setprio(1);
#pragma unroll
      for (int nt = 0; nt < 4; ++nt) {
        const int key = nt * 16 + l15;
        const int ksw = (key & 7) << 4;
        const short8 kf0 = *(const short8*)(Kh + key * 128 + ((g * 16) ^ ksw));
        const short8 kf1 = *(const short8*)(Kh + key * 128 + ((64 + g * 16) ^ ksw));
        f32x4 z = (f32x4){0.f, 0.f, 0.f, 0.f};
        sA[nt] = __builtin_amdgcn_mfma_f32_16x16x32_bf16(kf0, aq[0][0], z, 0, 0, 0);
        sA[nt] = __builtin_amdgcn_mfma_f32_16x16x32_bf16(kf1, aq[0][1], sA[nt], 0, 0, 0);
        sB[nt] = __builtin_amdgcn_mfma_f32_16x16x32_bf16(kf0, aq[1][0], z, 0, 0, 0);
        sB[nt] = __builtin_amdgcn_mfma_f32_16x16x32_bf16(kf1, aq[1][1], sB[nt], 0, 0, 0);
      }
      __builtin_amdgcn_s_setprio(0);
      short8 pbA[2], pbB[2];
#pragma unroll
      for (int c = 0; c < 2; ++c) {
        union { short8 s8; __hip_bfloat16 hhx[8]; } pa, pb;
#pragma unroll
        for (int e = 0; e < 8; ++e) {
          const int nt = 2 * c + (e >> 2);
          const float4 m4 = mb[hh * 4 + nt];
          const float mbe = (e & 3) == 0 ? m4.x : (e & 3) == 1 ? m4.y :
                            (e & 3) == 2 ? m4.z : m4.w;
          pa.hhx[e] = __float2bfloat16(EXP2F(fmaf(sA[nt][e & 3], SC_L2E, mbe)));
          pb.hhx[e] = __float2bfloat16(EXP2F(fmaf(sB[nt][e & 3], SC_L2E, mbe)));
        }
        pbA[c] = pa.s8; pbB[c] = pb.s8;
      }
      __builtin_amdgcn_s_setprio(1);
      laccA = __builtin_amdgcn_mfma_f32_16x16x32_bf16(ones8, pbA[0], laccA, 0, 0, 0);
      laccA = __builtin_amdgcn_mfma_f32_16x16x32_bf16(ones8, pbA[1], laccA, 0, 0, 0);
      laccB = __builtin_amdgcn_mfma_f32_16x16x32_bf16(ones8, pbB[0], laccB, 0, 0, 0);
      laccB = __builtin_amdgcn_mfma_f32_16x16x32_bf16(ones8, pbB[1], laccB, 0, 0, 0);
#pragma unroll
      for (int dt = 0; dt < 4; ++dt) {
        const int d = dt * 16 + l15;
        const int sw2 = (d & 7) << 4;
        const short8 v0 = *(const short8*)(Vh + d * 128 + ((g * 16) ^ sw2));
        const short8 v1 = *(const short8*)(Vh + d * 128 + ((64 + g * 16) ^ sw2));
        f32x4 oa = oaccA[dt], ob = oaccB[dt];
        oa = __builtin_amdgcn_mfma_f32_16x16x32_bf16(v0, pbA[0], oa, 0, 0, 0);
        oa = __builtin_amdgcn_mfma_f32_16x16x32_bf16(v1, pbA[1], oa, 0, 0, 0);
        ob = __builtin_amdgcn_mfma_f32_16x16x32_bf16(v0, pbB[0], ob, 0, 0, 0);
        ob = __builtin_amdgcn_mfma_f32_16x16x32_bf16(v1, pbB[1], ob, 0, 0, 0);
        oaccA[dt] = oa; oaccB[dt] = ob;
      }
      __builtin_amdgcn_s_setprio(0);
    }
    __syncthreads();
    cur ^= 1;
  }

  // epilogue: per q-tile, lacc rows all equal the full denominator
  const float rlA = 1.0f / laccA[0];
  const float rlB = 1.0f / laccB[0];
  float* orowA = out + ((size_t)(b * 2048 + arow0)) * 1024 + h * 64;
  float* orowB = orowA + 16 * 1024;
#pragma unroll
  for (int dt = 0; dt < 4; ++dt) {
    float4 stA, stB;
    stA.x = oaccA[dt][0] * rlA; stA.y = oaccA[dt][1] * rlA;
    stA.z = oaccA[dt][2] * rlA; stA.w = oaccA[dt][3] * rlA;
    stB.x = oaccB[dt][0] * rlB; stB.y = oaccB[dt][1] * rlB;
    stB.z = oaccB[dt][2] * rlB; stB.w = oaccB[dt][3] * rlB;
    *(float4*)(orowA + dt * 16 + g * 4) = stA;
    *(float4*)(orowB + dt * 16 + g * 4) = stB;
  }
}

// ---------------- launcher ----------------
extern "C" void kernel_launch(void* const* d_in, const int* in_sizes, int n_in,
                              void* d_out, int out_size, void* d_ws, size_t ws_size,
                              hipStream_t stream) {
  const float* q   = (const float*)d_in[0];
  const float* k   = (const float*)d_in[1];
  const float* v   = (const float*)d_in[2];
  const int* mask  = (const int*)d_in[3];
  const float* Wq  = (const float*)d_in[4];
  const float* bq  = (const float*)d_in[5];
  const float* Wk  = (const float*)d_in[6];
  const float* bk  = (const float*)d_in[7];
  const float* Wv  = (const float*)d_in[8];
  const float* bv  = (const float*)d_in[9];
  float* out = (float*)d_out;
  char* ws = (char*)d_ws;
  __hip_bfloat16* Xb = (__hip_bfloat16*)(ws);
  __hip_bfloat16* Wt = (__hip_bfloat16*)(ws + 25165824);
  __hip_bfloat16* Qb = (__hip_bfloat16*)(ws + 31457280);
  __hip_bfloat16* Kb = (__hip_bfloat16*)(ws + 39845888);
  __hip_bfloat16* Vt = (__hip_bfloat16*)(ws + 48234496);
  float* bias2      = (float*)(ws + 56623104);   // 4096 floats

  k_cvt<<<dim3(6912), dim3(256), 0, stream>>>(q, k, v, Xb, Wq, Wk, Wv, Wt, mask, bias2);
  k_proj<<<dim3(384), dim3(512), 0, stream>>>(Xb, Wt, bq, bk, bv, Qb, Kb, Vt);
  k_attn<<<dim3(512), dim3(256), 0, stream>>>(Qb, Kb, Vt, bias2, out);
}